// Round 7
// baseline (545.187 us; speedup 1.0000x reference)
//
#include <hip/hip_runtime.h>
#include <hip/hip_bf16.h>
#include <cstdint>

#define NEG_SLOPE 0.2f

typedef __attribute__((ext_vector_type(8))) short bf16x8;
typedef __attribute__((ext_vector_type(4))) float f32x4;

__device__ __forceinline__ float bf2f(uint32_t u) {
  union { float f; uint32_t i; } v;
  v.i = u << 16;
  return v.f;
}
__device__ __forceinline__ float lo16(uint32_t u) {
  union { float f; uint32_t i; } v;
  v.i = u << 16;
  return v.f;
}
__device__ __forceinline__ float hi16(uint32_t u) {
  union { float f; uint32_t i; } v;
  v.i = u & 0xffff0000u;
  return v.f;
}
__device__ __forceinline__ ushort f2bf(float f) {
  union { float f; uint32_t i; } v;
  v.f = f;
  uint32_t r = v.i + 0x7FFF + ((v.i >> 16) & 1);  // round-nearest-even
  return (ushort)(r >> 16);
}

// ---------------------------------------------------------------------------
// prep: cast x -> bf16, transpose+cast W1/W2/W3, CSR count pass, zero sums.
// ---------------------------------------------------------------------------
__global__ void prep_kernel(const float4* __restrict__ x,
                            uint2* __restrict__ x_bf, int n_x4,
                            const float* __restrict__ W1,
                            ushort* __restrict__ W1T,
                            const float* __restrict__ W2,
                            ushort* __restrict__ W2T,
                            const float* __restrict__ W3,
                            ushort* __restrict__ W3T,
                            const int* __restrict__ dst, int* __restrict__ cnt,
                            float* __restrict__ sums, int E) {
  int i = blockIdx.x * 256 + threadIdx.x;
  const int r0 = n_x4;
  const int r1 = r0 + 512 * 128;
  const int r2 = r1 + 64 * 512;
  const int r3 = r2 + 64 * 64;
  const int r4 = r3 + E;
  const int r5 = r4 + 64 * 64;
  if (i < r0) {
    float4 v = x[i];
    uint2 o;
    o.x = (uint32_t)f2bf(v.x) | ((uint32_t)f2bf(v.y) << 16);
    o.y = (uint32_t)f2bf(v.z) | ((uint32_t)f2bf(v.w) << 16);
    x_bf[i] = o;
  } else if (i < r1) {
    int idx = i - r0;
    int n = idx >> 7, k = idx & 127;
    W1T[idx] = f2bf(W1[(size_t)k * 512 + n]);
  } else if (i < r2) {
    int idx = i - r1;
    int n = idx >> 9, k = idx & 511;
    W2T[idx] = f2bf(W2[(size_t)k * 64 + n]);
  } else if (i < r3) {
    int idx = i - r2;
    int n = idx >> 6, k = idx & 63;
    W3T[idx] = f2bf(W3[(size_t)k * 64 + n]);
  } else if (i < r4) {
    atomicAdd(&cnt[dst[i - r3]], 1);
  } else if (i < r5) {
    sums[i - r4] = 0.f;
  }
}

// ---------------------------------------------------------------------------
// Fused dispatch: GEMM1(+al) for blocks [0, gemmBlocks), block-scan for the
// tail blocks. The two are independent (scan reads cnt from prep).
// ---------------------------------------------------------------------------
__global__ __launch_bounds__(256) void gemm1_scan_kernel(
    const ushort* __restrict__ A, const ushort* __restrict__ BT,
    ushort* __restrict__ C, const float* __restrict__ a1s,
    const float* __restrict__ a1d, float* __restrict__ al_s,
    float* __restrict__ al_d, int M, int gemmBlocks,
    const int* __restrict__ scan_in, int* __restrict__ scan_out,
    int* __restrict__ bsum, int n) {
  if (blockIdx.x >= gemmBlocks) {
    // ---- scan_block part ----
    __shared__ int sm[256];
    const int sb = blockIdx.x - gemmBlocks;
    int gid = sb * 256 + threadIdx.x;
    int v = (gid < n) ? scan_in[gid] : 0;
    sm[threadIdx.x] = v;
    __syncthreads();
    for (int off = 1; off < 256; off <<= 1) {
      int t = (threadIdx.x >= off) ? sm[threadIdx.x - off] : 0;
      __syncthreads();
      sm[threadIdx.x] += t;
      __syncthreads();
    }
    if (gid < n) scan_out[gid] = sm[threadIdx.x];
    if (threadIdx.x == 255) bsum[sb] = sm[255];
    return;
  }
  // ---- gemm1 + al part ----
  const int K = 128;
  const int wave = threadIdx.x >> 6;
  const int lane = threadIdx.x & 63;
  const int bx = blockIdx.x & 3;
  const int by = blockIdx.x >> 2;
  const int rt = by * 4 + wave;
  const int r0 = rt * 16;
  if (r0 >= M) return;
  const int n0 = bx * 128;
  const int l15 = lane & 15, q = lane >> 4;
  const ushort* Ap = A + (size_t)(r0 + l15) * K + q * 8;
  f32x4 acc[8] = {};
  for (int k0 = 0; k0 < K; k0 += 32) {
    bf16x8 a = *(const bf16x8*)(Ap + k0);
#pragma unroll
    for (int j = 0; j < 8; ++j) {
      const bf16x8 b =
          *(const bf16x8*)(BT + (size_t)(n0 + j * 16 + l15) * K + q * 8 + k0);
      acc[j] = __builtin_amdgcn_mfma_f32_16x16x32_bf16(a, b, acc[j], 0, 0, 0);
    }
  }
#pragma unroll
  for (int j = 0; j < 8; ++j)
#pragma unroll
    for (int r = 0; r < 4; ++r) {
      int row = r0 + q * 4 + r;
      C[(size_t)row * 512 + n0 + j * 16 + l15] = f2bf(acc[j][r]);
    }
  float als_p[2][4] = {{0.f}};
  float ald_p[2][4] = {{0.f}};
#pragma unroll
  for (int j = 0; j < 8; ++j) {
    int head = bx * 2 + (j >> 2);
    int cih = (j & 3) * 16 + l15;
    float wsc = a1s[head * 64 + cih];
    float wdc = a1d[head * 64 + cih];
#pragma unroll
    for (int r = 0; r < 4; ++r) {
      als_p[j >> 2][r] = fmaf(acc[j][r], wsc, als_p[j >> 2][r]);
      ald_p[j >> 2][r] = fmaf(acc[j][r], wdc, ald_p[j >> 2][r]);
    }
  }
#pragma unroll
  for (int g = 0; g < 2; ++g)
#pragma unroll
    for (int r = 0; r < 4; ++r) {
      float vs = als_p[g][r], vd = ald_p[g][r];
#pragma unroll
      for (int off = 1; off < 16; off <<= 1) {
        vs += __shfl_xor(vs, off);
        vd += __shfl_xor(vd, off);
      }
      if (l15 == 0) {
        int row = r0 + q * 4 + r;
        al_s[(size_t)row * 8 + bx * 2 + g] = vs;
        al_d[(size_t)row * 8 + bx * 2 + g] = vd;
      }
    }
}

// ---------------------------------------------------------------------------
// GEMM (N=64) + fused al (H=1): C[M,64] = A[M,K] @ BT[64,K].
// ---------------------------------------------------------------------------
__global__ __launch_bounds__(256) void gemm_n64_al(
    const ushort* __restrict__ A, const ushort* __restrict__ BT,
    ushort* __restrict__ C, const float* __restrict__ asrc,
    const float* __restrict__ adst, float* __restrict__ al_s,
    float* __restrict__ al_d, int M, int K) {
  const int wave = threadIdx.x >> 6;
  const int lane = threadIdx.x & 63;
  const int rt = blockIdx.y * 4 + wave;
  const int r0 = rt * 16;
  if (r0 >= M) return;
  const int l15 = lane & 15, q = lane >> 4;
  const ushort* Ap = A + (size_t)(r0 + l15) * K + q * 8;
  f32x4 acc[4] = {};
  for (int k0 = 0; k0 < K; k0 += 32) {
    bf16x8 a = *(const bf16x8*)(Ap + k0);
#pragma unroll
    for (int j = 0; j < 4; ++j) {
      const bf16x8 b =
          *(const bf16x8*)(BT + (size_t)(j * 16 + l15) * K + q * 8 + k0);
      acc[j] = __builtin_amdgcn_mfma_f32_16x16x32_bf16(a, b, acc[j], 0, 0, 0);
    }
  }
#pragma unroll
  for (int j = 0; j < 4; ++j)
#pragma unroll
    for (int r = 0; r < 4; ++r) {
      int row = r0 + q * 4 + r;
      C[(size_t)row * 64 + j * 16 + l15] = f2bf(acc[j][r]);
    }
  float als_p[4] = {0.f, 0.f, 0.f, 0.f};
  float ald_p[4] = {0.f, 0.f, 0.f, 0.f};
#pragma unroll
  for (int j = 0; j < 4; ++j) {
    float wsc = asrc[j * 16 + l15];
    float wdc = adst[j * 16 + l15];
#pragma unroll
    for (int r = 0; r < 4; ++r) {
      als_p[r] = fmaf(acc[j][r], wsc, als_p[r]);
      ald_p[r] = fmaf(acc[j][r], wdc, ald_p[r]);
    }
  }
#pragma unroll
  for (int r = 0; r < 4; ++r) {
    float vs = als_p[r], vd = ald_p[r];
#pragma unroll
    for (int off = 1; off < 16; off <<= 1) {
      vs += __shfl_xor(vs, off);
      vd += __shfl_xor(vd, off);
    }
    if (l15 == 0) {
      int row = r0 + q * 4 + r;
      al_s[row] = vs;
      al_d[row] = vd;
    }
  }
}

__global__ void scan_final2(const int* __restrict__ inc,
                            const int* __restrict__ bsum,
                            int* __restrict__ indptr, int* __restrict__ fill,
                            int n) {
  __shared__ int sm[256];
  const int t = threadIdx.x, bx = blockIdx.x;
  sm[t] = (t < bx) ? bsum[t] : 0;  // gridDim <= 256
  __syncthreads();
  for (int off = 128; off; off >>= 1) {
    if (t < off) sm[t] += sm[t + off];
    __syncthreads();
  }
  const int prefix = sm[0];
  int gid = bx * 256 + t;
  if (gid < n) {
    int val = inc[gid] + prefix;
    indptr[gid + 1] = val;
    fill[gid + 1] = val;
  }
  if (gid == 0) {
    indptr[0] = 0;
    fill[0] = 0;
  }
}

__global__ void scatter_kernel(const int* __restrict__ src,
                               const int* __restrict__ dst,
                               int* __restrict__ fill,
                               int* __restrict__ csr_src, int E) {
  int e = blockIdx.x * 256 + threadIdx.x;
  if (e < E) {
    int pos = atomicAdd(&fill[dst[e]], 1);
    csr_src[pos] = src[e];
  }
}

// ---------------------------------------------------------------------------
// Attention layer 1, CHANNEL-HALF pass: processes heads hbase..hbase+3
// (channels hbase*64 .. hbase*64+255). One wave per dst node. Two temporal
// passes over the device shrink the gather working set 51.2MB -> 25.6MB to
// raise per-XCD L2 hit rate (attn1 is L2-fill-path bound at ~3.35 TB/s).
// Alpha stage: lane j -> edge slot j>>2 (16 slots), local head j&3.
// Accumulate: lane l -> 4 channels (l*4), local head l>>4. 16 dwordx2 row
// loads in flight per group.
// ---------------------------------------------------------------------------
__global__ __launch_bounds__(256) void attn1_half_kernel(
    const int* __restrict__ indptr, const int* __restrict__ csr_src,
    const float* __restrict__ al_s, const float* __restrict__ al_d,
    const ushort* __restrict__ h1, const float* __restrict__ b1,
    ushort* __restrict__ out1, int Nn, int hbase) {
  const int w = (blockIdx.x * 256 + threadIdx.x) >> 6;
  const int l = threadIdx.x & 63;
  if (w >= Nn) return;
  const int d = w;
  const int start = indptr[d];
  const int deg = indptr[d + 1] - start;
  const int total = deg + 1;  // + self loop
  const int slot = l >> 2;    // alpha-stage edge slot 0..15
  const int hh = l & 3;       // alpha-stage local head
  const int headl = l >> 4;   // accumulation local head
  const float ald_c = al_d[(size_t)d * 8 + hbase + hh];

  float acc[4] = {0.f, 0.f, 0.f, 0.f};
  float den = 0.f;
  const size_t colbase = (size_t)hbase * 64;  // 0 or 256
  const ushort* h1l = h1 + colbase + l * 4;

  for (int e0 = 0; e0 < total; e0 += 16) {
    const int el = e0 + slot;
    int s_j = d;
    float u = 0.f;
    if (el < total) {
      s_j = (el < deg) ? csr_src[start + el] : d;
      float v = al_s[(size_t)s_j * 8 + hbase + hh] + ald_c;
      v = fmaxf(v, NEG_SLOPE * v);
      u = __expf(v);
      den += u;
    }
#pragma unroll
    for (int e = 0; e < 16; ++e) {
      const float a = __shfl(u, e * 4 + headl);
      const int s = __shfl(s_j, e * 4);
      const uint2 uu = *(const uint2*)(h1l + (size_t)s * 512);
      acc[0] = fmaf(a, lo16(uu.x), acc[0]);
      acc[1] = fmaf(a, hi16(uu.x), acc[1]);
      acc[2] = fmaf(a, lo16(uu.y), acc[2]);
      acc[3] = fmaf(a, hi16(uu.y), acc[3]);
    }
  }
  // den reduction over slot bits (xor 4,8,16,32 preserve l&3)
  den += __shfl_xor(den, 4);
  den += __shfl_xor(den, 8);
  den += __shfl_xor(den, 16);
  den += __shfl_xor(den, 32);
  const float inv = 1.f / __shfl(den, headl);  // lane headl has hh==headl

  const float4 bb = *(const float4*)(b1 + colbase + l * 4);
  float o[4];
  o[0] = acc[0] * inv + bb.x;
  o[1] = acc[1] * inv + bb.y;
  o[2] = acc[2] * inv + bb.z;
  o[3] = acc[3] * inv + bb.w;
#pragma unroll
  for (int k = 0; k < 4; ++k) o[k] = (o[k] > 0.f) ? o[k] : __expf(o[k]) - 1.f;
  uint2 st;
  st.x = (uint32_t)f2bf(o[0]) | ((uint32_t)f2bf(o[1]) << 16);
  st.y = (uint32_t)f2bf(o[2]) | ((uint32_t)f2bf(o[3]) << 16);
  *(uint2*)(out1 + (size_t)d * 512 + colbase + l * 4) = st;
}

// ---------------------------------------------------------------------------
// Attention layer 2: H=1, C=64, h bf16. One wave per node -> out bf16.
// ---------------------------------------------------------------------------
__global__ __launch_bounds__(256) void attn_h1_kernel(
    const int* __restrict__ indptr, const int* __restrict__ csr_src,
    const float* __restrict__ al_s, const float* __restrict__ al_d,
    const ushort* __restrict__ hin, const float* __restrict__ bias,
    ushort* __restrict__ outp, int Nn) {
  int w = (blockIdx.x * 256 + threadIdx.x) >> 6;
  int lane = threadIdx.x & 63;
  if (w >= Nn) return;
  const int d = w;
  const int start = indptr[d];
  const int deg = indptr[d + 1] - start;
  const int total = deg + 1;
  const float ald = al_d[d];

  float acc = 0.f, den = 0.f;
  for (int e0 = 0; e0 < total; e0 += 64) {
    int e = e0 + lane;
    int s_j = d;
    float u = 0.f;
    if (e < total) {
      s_j = (e < deg) ? csr_src[start + e] : d;
      float v = al_s[s_j] + ald;
      v = fmaxf(v, NEG_SLOPE * v);
      u = __expf(v);
      den += u;
    }
    int ne = min(64, total - e0);
    for (int j = 0; j < ne; j += 8) {
      float av[8];
      int sv[8];
#pragma unroll
      for (int k = 0; k < 8; ++k) {
        av[k] = __shfl(u, j + k);
        sv[k] = __shfl(s_j, j + k);
      }
      float hv[8];
#pragma unroll
      for (int k = 0; k < 8; ++k)
        hv[k] = bf2f(hin[(size_t)sv[k] * 64 + lane]);
#pragma unroll
      for (int k = 0; k < 8; ++k) acc = fmaf(av[k], hv[k], acc);
    }
  }
#pragma unroll
  for (int off = 32; off; off >>= 1) den += __shfl_xor(den, off);
  float v = acc / den + bias[lane];
  v = (v > 0.f) ? v : __expf(v) - 1.f;
  outp[(size_t)d * 64 + lane] = f2bf(v);
}

// ---------------------------------------------------------------------------
// Attention layer 3 + pooling: accumulate into per-graph sums via atomics.
// ---------------------------------------------------------------------------
__global__ __launch_bounds__(256) void attn_h1_pool_kernel(
    const int* __restrict__ indptr, const int* __restrict__ csr_src,
    const float* __restrict__ al_s, const float* __restrict__ al_d,
    const ushort* __restrict__ hin, const float* __restrict__ bias,
    const int* __restrict__ batch, float* __restrict__ sums, int Nn) {
  int w = (blockIdx.x * 256 + threadIdx.x) >> 6;
  int lane = threadIdx.x & 63;
  if (w >= Nn) return;
  const int d = w;
  const int start = indptr[d];
  const int deg = indptr[d + 1] - start;
  const int total = deg + 1;
  const float ald = al_d[d];

  float acc = 0.f, den = 0.f;
  for (int e0 = 0; e0 < total; e0 += 64) {
    int e = e0 + lane;
    int s_j = d;
    float u = 0.f;
    if (e < total) {
      s_j = (e < deg) ? csr_src[start + e] : d;
      float v = al_s[s_j] + ald;
      v = fmaxf(v, NEG_SLOPE * v);
      u = __expf(v);
      den += u;
    }
    int ne = min(64, total - e0);
    for (int j = 0; j < ne; j += 8) {
      float av[8];
      int sv[8];
#pragma unroll
      for (int k = 0; k < 8; ++k) {
        av[k] = __shfl(u, j + k);
        sv[k] = __shfl(s_j, j + k);
      }
      float hv[8];
#pragma unroll
      for (int k = 0; k < 8; ++k)
        hv[k] = bf2f(hin[(size_t)sv[k] * 64 + lane]);
#pragma unroll
      for (int k = 0; k < 8; ++k) acc = fmaf(av[k], hv[k], acc);
    }
  }
#pragma unroll
  for (int off = 32; off; off >>= 1) den += __shfl_xor(den, off);
  float v = acc / den + bias[lane];
  v = (v > 0.f) ? v : __expf(v) - 1.f;
  atomicAdd(&sums[batch[d] * 64 + lane], v);
}

// ---------------------------------------------------------------------------
// Final FC on pooled sums. One block.
// ---------------------------------------------------------------------------
__global__ __launch_bounds__(256) void fc_kernel(
    const float* __restrict__ sums, const int* __restrict__ batch, int Nn,
    const float* __restrict__ fcW, const float* __restrict__ fcb,
    float* __restrict__ out) {
  __shared__ int lb[65];
  __shared__ float inv_cnt[64];
  int tid = threadIdx.x;
  if (tid <= 64) {
    int lo = 0, hi = Nn;
    while (lo < hi) {
      int mid = (lo + hi) >> 1;
      if (batch[mid] < tid) lo = mid + 1; else hi = mid;
    }
    lb[tid] = lo;
  }
  __syncthreads();
  if (tid < 64) inv_cnt[tid] = 1.f / fmaxf((float)(lb[tid + 1] - lb[tid]), 1.f);
  __syncthreads();
  for (int i = tid; i < 64 * 10; i += 256) {
    int g = i / 10, o = i % 10;
    float acc = fcb[o];
    float inv = inv_cnt[g];
    for (int c = 0; c < 64; ++c)
      acc = fmaf(sums[g * 64 + c] * inv, fcW[c * 10 + o], acc);
    out[i] = acc;
  }
}

// ---------------------------------------------------------------------------
extern "C" void kernel_launch(void* const* d_in, const int* in_sizes, int n_in,
                              void* d_out, int out_size, void* d_ws,
                              size_t ws_size, hipStream_t stream) {
  const float* x = (const float*)d_in[0];
  const int* ei = (const int*)d_in[1];
  const int* batch = (const int*)d_in[2];
  const float* W1 = (const float*)d_in[3];
  const float* a1s = (const float*)d_in[4];
  const float* a1d = (const float*)d_in[5];
  const float* b1 = (const float*)d_in[6];
  const float* W2 = (const float*)d_in[7];
  const float* a2s = (const float*)d_in[8];
  const float* a2d = (const float*)d_in[9];
  const float* b2 = (const float*)d_in[10];
  const float* W3 = (const float*)d_in[11];
  const float* a3s = (const float*)d_in[12];
  const float* a3d = (const float*)d_in[13];
  const float* b3 = (const float*)d_in[14];
  const float* fcW = (const float*)d_in[15];
  const float* fcb = (const float*)d_in[16];
  float* out = (float*)d_out;

  const int N = in_sizes[0] / 128;  // 50000
  const int E = in_sizes[1] / 2;    // 800000
  const int* srcp = ei;
  const int* dstp = ei + E;

  // --- workspace layout ---
  char* ws = (char*)d_ws;
  size_t off = 0;
  auto alloc = [&](size_t bytes) -> void* {
    off = (off + 255) & ~(size_t)255;
    void* p = ws + off;
    off += bytes;
    return p;
  };
  ushort* x_bf = (ushort*)alloc((size_t)N * 128 * 2);
  ushort* W1T = (ushort*)alloc(512 * 128 * 2);
  ushort* W2T = (ushort*)alloc(64 * 512 * 2);
  ushort* W3T = (ushort*)alloc(64 * 64 * 2);
  ushort* h1 = (ushort*)alloc((size_t)N * 512 * 2);  // reused: h2/out2/h3
  ushort* out1 = (ushort*)alloc((size_t)N * 512 * 2);
  float* al_s1 = (float*)alloc((size_t)N * 8 * 4);
  float* al_d1 = (float*)alloc((size_t)N * 8 * 4);
  float* al_s2 = (float*)alloc((size_t)N * 4);
  float* al_d2 = (float*)alloc((size_t)N * 4);
  float* al_s3 = (float*)alloc((size_t)N * 4);
  float* al_d3 = (float*)alloc((size_t)N * 4);
  int* cnt = (int*)alloc((size_t)N * 4);
  int* fill = (int*)alloc((size_t)(N + 1) * 4);
  int* indptr = (int*)alloc((size_t)(N + 1) * 4);
  int* csr = (int*)alloc((size_t)E * 4);
  int* incbuf = (int*)alloc((size_t)N * 4);
  int* bsum = (int*)alloc(1024 * 4);
  float* sums = (float*)alloc(64 * 64 * 4);

  // aliases into the (dead-after-attn1) h1 region
  ushort* h2 = h1;
  ushort* out2 = h1 + (size_t)N * 64;
  ushort* h3 = h1 + (size_t)2 * N * 64;

  hipMemsetAsync(cnt, 0, (size_t)N * 4, stream);

  const int scan_blocks = (N + 255) / 256;  // 196 (<256 required)
  const int row_blocks = (N / 16 + 3) / 4;  // 782

  // prep: x cast + weight transposes + CSR count + sums zero
  const int n_x4 = N * 128 / 4;
  const int prep_total = n_x4 + 512 * 128 + 64 * 512 + 64 * 64 + E + 64 * 64;
  prep_kernel<<<(prep_total + 255) / 256, 256, 0, stream>>>(
      (const float4*)x, (uint2*)x_bf, n_x4, W1, W1T, W2, W2T, W3, W3T, dstp,
      cnt, sums, E);

  // GEMM1 + al1, fused with block-scan of cnt (independent work)
  const int gemmBlocks = 4 * row_blocks;
  gemm1_scan_kernel<<<gemmBlocks + scan_blocks, 256, 0, stream>>>(
      x_bf, W1T, h1, a1s, a1d, al_s1, al_d1, N, gemmBlocks, cnt, incbuf, bsum,
      N);
  scan_final2<<<scan_blocks, 256, 0, stream>>>(incbuf, bsum, indptr, fill, N);
  scatter_kernel<<<(E + 255) / 256, 256, 0, stream>>>(srcp, dstp, fill, csr, E);

  // Layer 1 attention: two channel-half passes (heads 0-3, then 4-7)
  attn1_half_kernel<<<(N + 3) / 4, 256, 0, stream>>>(indptr, csr, al_s1, al_d1,
                                                     h1, b1, out1, N, 0);
  attn1_half_kernel<<<(N + 3) / 4, 256, 0, stream>>>(indptr, csr, al_s1, al_d1,
                                                     h1, b1, out1, N, 4);

  // Layer 2
  gemm_n64_al<<<dim3(1, row_blocks), 256, 0, stream>>>(out1, W2T, h2, a2s, a2d,
                                                       al_s2, al_d2, N, 512);
  attn_h1_kernel<<<(N + 3) / 4, 256, 0, stream>>>(indptr, csr, al_s2, al_d2, h2,
                                                  b2, out2, N);

  // Layer 3
  gemm_n64_al<<<dim3(1, row_blocks), 256, 0, stream>>>(out2, W3T, h3, a3s, a3d,
                                                       al_s3, al_d3, N, 64);
  attn_h1_pool_kernel<<<(N + 3) / 4, 256, 0, stream>>>(
      indptr, csr, al_s3, al_d3, h3, b3, batch, sums, N);

  // Final FC
  fc_kernel<<<1, 256, 0, stream>>>(sums, batch, N, fcW, fcb, out);
}